// Round 12
// baseline (155.001 us; speedup 1.0000x reference)
//
#include <hip/hip_runtime.h>
#include <hip/hip_bf16.h>
#include <math.h>

#define BB 4
#define TT 4096
#define CC 1024
#define HH 64

typedef __attribute__((ext_vector_type(8))) short short8;          // MFMA A/B frag (8 bf16)
typedef __attribute__((ext_vector_type(8))) unsigned short ushort8;
typedef __attribute__((ext_vector_type(4))) float f32x4;           // MFMA C/D frag
typedef __attribute__((ext_vector_type(2))) unsigned int uint2v;   // 8B mover
typedef __attribute__((ext_vector_type(4))) unsigned int uint4v;   // 16B pack

// RNE float->bf16 (bit-trick; used in non-hot paths)
__device__ inline unsigned short f2bf(float f) {
    unsigned int u = __builtin_bit_cast(unsigned int, f);
    unsigned int r = u + 0x7fffu + ((u >> 16) & 1u);
    return (unsigned short)(r >> 16);
}

// packed RNE float2->bf16x2 (hot loops; identical rounding to f2bf)
__device__ inline unsigned int cvtpk(float lo, float hi) {
    unsigned int r;
    asm("v_cvt_pk_bf16_f32 %0, %1, %2" : "=v"(r) : "v"(lo), "v"(hi));
    return r;
}

// native 2^x (single VOP1 transcendental)
__device__ inline float exp2v(float x) {
    float r;
    asm("v_exp_f32 %0, %1" : "=v"(r) : "v"(x));
    return r;
}

// async global->LDS, 16B per lane. LDS dest = wave-uniform base + lane*16.
__device__ inline void gll16(const void* g, void* l) {
    __builtin_amdgcn_global_load_lds(
        (const __attribute__((address_space(1))) unsigned int*)g,
        (__attribute__((address_space(3))) unsigned int*)l,
        16, 0, 0);
}

// scratch-slot offset within a batch for 16-row strip qs >= 64
__device__ inline int soff_strip(int qs) {
    if (qs < 128) return (qs - 64) * 2;
    if (qs < 192) return 128 + (qs - 128) * 3;
    return 320 + (qs - 192) * 4;
}

// ---------------------------------------------------------------------------
// Kernel 0: W -> frag-linear bf16 layout Wf (unchanged, proven).
// ---------------------------------------------------------------------------
__global__ __launch_bounds__(256) void wtrans_kernel(
    const float* __restrict__ Wq,
    const float* __restrict__ Wk,
    const float* __restrict__ Wv,
    unsigned short* __restrict__ Wf)
{
    const int t = blockIdx.x * 256 + threadIdx.x;   // 0..24575
    const int lane = t & 63;
    const int ntl  = (t >> 6) % 12;
    const int kt   = t / 768;
    const int quad = lane >> 4, n = lane & 15;
    const int m    = ntl >> 2;
    const int col  = (ntl & 3) * 16 + n;
    const float* src = (m == 0) ? Wq : (m == 1) ? Wk : Wv;
    ushort8 u;
#pragma unroll
    for (int j = 0; j < 8; ++j)
        u[j] = f2bf(src[(kt * 32 + quad * 8 + j) * 64 + col]);
    *(ushort8*)(Wf + (size_t)t * 8) = u;
}

// ---------------------------------------------------------------------------
// Kernel 1: QKV GEMM. R17 depth-2 counted-vmcnt structure + R20 exp2-domain
// Q pre-scale (unchanged from the 145.6us best).
// ---------------------------------------------------------------------------
__global__ __launch_bounds__(512, 2) void qkv_gemm(
    const float* __restrict__ x,
    const unsigned short* __restrict__ Wf,
    unsigned short* __restrict__ Qb,
    unsigned short* __restrict__ Kf,
    unsigned short* __restrict__ Vf)
{
    // buf bb at bb*40960: x[64][64] f32 @ +0 (16KB), Wf 24 frags @ +16384 (24KB)
    __shared__ __align__(16) unsigned char smem[122880];   // 3 bufs x 40KB
    float (*Tl)[200] = (float (*)[200])smem;   // epilogue overlay [64][200] (51.2KB)

    const int tid  = threadIdx.x;
    const int lane = tid & 63;
    const int wave = tid >> 6;          // 0..7
    const int n    = lane & 15;
    const int quad = lane >> 4;
    const int mt   = wave & 3;          // m-tile (16 rows)
    const int ch   = wave >> 2;         // col half (96 cols)

    const int row0g = blockIdx.x * 64;  // global row base (full st strip)
    const int b     = row0g >> 12;
    const int st    = (row0g & (TT - 1)) >> 6;

    const char* xg = (const char*)(x + (size_t)row0g * CC);
    const char* wg = (const char*)Wf;

    f32x4 acc[6];
#pragma unroll
    for (int i = 0; i < 6; ++i) acc[i] = (f32x4){0.f, 0.f, 0.f, 0.f};

    // ---- staging: 5 global_load_lds per thread per K-step ----
    auto stage = [&](int bb, int s) {
        unsigned char* base = smem + bb * 40960;
#pragma unroll
        for (int i = 0; i < 2; ++i) {
            const int rr = (i * 8 + wave) * 4 + (lane >> 4);
            const int cb = ((lane & 15) * 16) ^ ((rr & 7) << 4);
            gll16(xg + (size_t)rr * 4096 + s * 256 + cb,
                  base + (i * 8 + wave) * 1024);
        }
#pragma unroll
        for (int i = 0; i < 3; ++i) {
            const int off = (i * 8 + wave) * 1024;
            gll16(wg + (size_t)s * 24576 + off + lane * 16,
                  base + 16384 + off);
        }
    };

    // ---- compute one K-step from buf bb (LDS only; no VMEM ops) ----
    auto compute = [&](int bb) {
        const unsigned char* xb = smem + bb * 40960;
        const unsigned char* wb = xb + 16384;
        const int row = mt * 16 + n;
        const int swz = (n & 7) << 4;
#pragma unroll
        for (int ktl = 0; ktl < 2; ++ktl) {
            const int c0 = (ktl * 128 + quad * 32) ^ swz;
            const int c1 = (ktl * 128 + quad * 32 + 16) ^ swz;
            const float4 f0 = *(const float4*)(xb + row * 256 + c0);
            const float4 f1 = *(const float4*)(xb + row * 256 + c1);
            uint4v u;
            u[0] = cvtpk(f0.x, f0.y);
            u[1] = cvtpk(f0.z, f0.w);
            u[2] = cvtpk(f1.x, f1.y);
            u[3] = cvtpk(f1.z, f1.w);
            const short8 a0 = __builtin_bit_cast(short8, u);
#pragma unroll
            for (int t = 0; t < 6; ++t) {
                const int g = ch * 6 + t;
                const short8 bwv = *(const short8*)(wb + (ktl * 12 + g) * 1024 + lane * 16);
                acc[t] = __builtin_amdgcn_mfma_f32_16x16x32_bf16(a0, bwv, acc[t], 0, 0, 0);
            }
        }
    };

    // ---- counted-vmcnt pipelined K loop (16 steps of K=64, depth 2) ----
    stage(0, 0);
    stage(1, 1);
#pragma unroll
    for (int s = 0; s < 16; ++s) {
        if (s + 2 < 16) stage((s + 2) % 3, s + 2);
        if (s <= 13)      asm volatile("s_waitcnt vmcnt(10)" ::: "memory");
        else if (s == 14) asm volatile("s_waitcnt vmcnt(5)"  ::: "memory");
        else              asm volatile("s_waitcnt vmcnt(0)"  ::: "memory");
        __builtin_amdgcn_sched_barrier(0);
        __builtin_amdgcn_s_barrier();     // all waves' stage-s data in LDS
        compute(s % 3);
        __builtin_amdgcn_s_barrier();     // all waves done reading buf s%3
    }

    // ---- deposit acc into Tl (overlays staging; all reads are done) ----
#pragma unroll
    for (int t = 0; t < 6; ++t) {
        const int g   = ch * 6 + t;
        const int col = (g >> 2) * 64 + (g & 3) * 16 + n;
#pragma unroll
        for (int r = 0; r < 4; ++r)
            Tl[mt * 16 + quad * 4 + r][col] = acc[t][r];
    }
    __syncthreads();

    // ---- epilogue ----
    // Q: row-major bf16, pre-scaled by C^-0.5 * log2(e) for exp2-domain attn.
    {
        const int row = tid & 63;
        const int c0  = (tid >> 6) * 8;
        const float qsc = 0.045084220f;   // (1/32) * log2(e)
        uint4v w4;
        w4[0] = cvtpk(Tl[row][c0]     * qsc, Tl[row][c0 + 1] * qsc);
        w4[1] = cvtpk(Tl[row][c0 + 2] * qsc, Tl[row][c0 + 3] * qsc);
        w4[2] = cvtpk(Tl[row][c0 + 4] * qsc, Tl[row][c0 + 5] * qsc);
        w4[3] = cvtpk(Tl[row][c0 + 6] * qsc, Tl[row][c0 + 7] * qsc);
        *(uint4v*)(Qb + (size_t)(row0g + row) * HH + c0) = w4;
    }
    // K frag-linear: wave -> frag (mt2 = wave>>1, kk = wave&1)
    {
        const int mt2 = wave >> 1, kk = wave & 1;
        ushort8 u;
#pragma unroll
        for (int j = 0; j < 8; ++j)
            u[j] = f2bf(Tl[mt2 * 16 + n][64 + kk * 32 + quad * 8 + j]);
        const size_t r = (size_t)(((b * 64 + st) * 4 + mt2) * 2 + kk) * 64 + lane;
        *(ushort8*)(Kf + r * 8) = u;
    }
    // V frag-linear (V^T frags): wave -> frag (ht = wave>>1, kv = wave&1)
    {
        const int ht = wave >> 1, kv = wave & 1;
        ushort8 u;
#pragma unroll
        for (int j = 0; j < 8; ++j)
            u[j] = f2bf(Tl[kv * 32 + quad * 8 + j][128 + ht * 16 + n]);
        const size_t r = (size_t)(((b * 64 + st) * 4 + ht) * 2 + kv) * 64 + lane;
        *(ushort8*)(Vf + r * 8) = u;
    }
}

// ---------------------------------------------------------------------------
// Kernel 2: flash attention. R21: d-split wave doubling. attn measured
// latency-bound at 2.5 waves/SIMD (VALUBusy 51%, Occ 15%, Mfma 12%); the
// 640-unit/batch decomposition caps wave count. Split each (qs,ci) unit
// across TWO waves by head-dim half: each wave duplicates QK^T + softmax
// (cheap; MFMA/L2 have headroom) but loads only its 2 V frags and computes
// 2 of 4 O frags. No cross-wave comm (both compute identical l; dhalf=0
// writes it). scr slots shared via disjoint 16-float slices -> scr layout
// and combine UNCHANGED. Grid 640->1280 blocks = 5120 waves = 5 waves/SIMD.
// Keeps R20: exp2-domain softmax, cvtpk P-packing, padded Ps, reversal.
// ---------------------------------------------------------------------------
__global__ __launch_bounds__(256) void attn_kernel(
    const unsigned short* __restrict__ Qb,
    const unsigned short* __restrict__ Kf,
    const unsigned short* __restrict__ Vf,
    float* __restrict__ out,
    float* __restrict__ scr)
{
    __shared__ unsigned short Ps[4][2][16][76];   // per-wave dbuf P strip (padded)

    const int tid  = threadIdx.x;
    const int lane = tid & 63;
    const int wave = tid >> 6;
    const int n    = lane & 15;
    const int quad = lane >> 4;

    const int wid = blockIdx.x * 4 + wave;     // 0..5119
    const int b   = wid / 1280;
    const int u2  = wid - b * 1280;            // 0..1279
    const int dhalf = u2 & 1;                  // head-dim half (ht pair)
    const int u   = 639 - (u2 >> 1);           // reversed: long chunks first

    // prefix-sum inverse: u -> (qs, ci), nc(qs) = (qs>>2 + 16)>>4
    int qs, ci;
    if (u < 64)        { qs = u;                  ci = 0; }
    else if (u < 192)  { const int v = u - 64;  qs = 64  + (v >> 1); ci = v & 1; }
    else if (u < 384)  { const int v = u - 192; const int d = v / 3;
                         qs = 128 + d;            ci = v - 3 * d; }
    else               { const int v = u - 384; qs = 192 + (v >> 2); ci = v & 3; }

    const int stmax = qs >> 2;
    const int st0   = ci << 4;
    const int stEnd = min(stmax, st0 + 15);
    const int nc    = (stmax + 16) >> 4;
    const int qrow  = qs * 16 + n;

    // Q^T B-frags resident (Q pre-scaled by C^-0.5 * log2e)
    const unsigned short* qp = Qb + ((size_t)b * TT + qrow) * HH;
    const short8 bQ0 = *(const short8*)(qp + quad * 8);
    const short8 bQ1 = *(const short8*)(qp + 32 + quad * 8);

    const unsigned short* KfB = Kf + (size_t)b * 262144;
    const unsigned short* VfB = Vf + (size_t)b * 262144;

    f32x4 O[2];
#pragma unroll
    for (int h = 0; h < 2; ++h) O[h] = (f32x4){0.f, 0.f, 0.f, 0.f};
    float l = 0.f;

    // preload K frags for st0
    short8 kA[4], kB[4];
#pragma unroll
    for (int mt = 0; mt < 4; ++mt) {
        const unsigned short* kp = KfB + (size_t)((st0 * 4 + mt) * 2) * 512 + lane * 8;
        kA[mt] = *(const short8*)(kp);
        kB[mt] = *(const short8*)(kp + 512);
    }

    for (int st = st0; st <= stEnd; ++st) {
        // ---- S^T = K Q^T from resident K frags (log2-domain) ----
        f32x4 S[4];
#pragma unroll
        for (int mt = 0; mt < 4; ++mt) {
            f32x4 acc = (f32x4){0.f, 0.f, 0.f, 0.f};
            acc = __builtin_amdgcn_mfma_f32_16x16x32_bf16(kA[mt], bQ0, acc, 0, 0, 0);
            acc = __builtin_amdgcn_mfma_f32_16x16x32_bf16(kB[mt], bQ1, acc, 0, 0, 0);
            S[mt] = acc;
        }

        // ---- V frags (this wave's 2 ht only) ----
        short8 vA[2], vB[2];
#pragma unroll
        for (int h = 0; h < 2; ++h) {
            const int ht = dhalf * 2 + h;
            const unsigned short* vp = VfB + (size_t)((st * 4 + ht) * 2) * 512 + lane * 8;
            vA[h] = *(const short8*)(vp);
            vB[h] = *(const short8*)(vp + 512);
        }
        // ---- K prefetch for st+1 ----
        if (st < stEnd) {
#pragma unroll
            for (int mt = 0; mt < 4; ++mt) {
                const unsigned short* kp = KfB + (size_t)(((st + 1) * 4 + mt) * 2) * 512 + lane * 8;
                kA[mt] = *(const short8*)(kp);
                kB[mt] = *(const short8*)(kp + 512);
            }
        }

        // ---- causal mask (diag tile): element row = s, col = qrow ----
        if (st == stmax) {
#pragma unroll
            for (int mt = 0; mt < 4; ++mt) {
                const int sg = st * 64 + mt * 16 + quad * 4;
#pragma unroll
                for (int r = 0; r < 4; ++r)
                    if (sg + r > qrow) S[mt][r] = -INFINITY;
            }
        }

        // ---- softmax accumulate: p = 2^min(S, 30*log2e); exp2(-inf)=0 ----
#pragma unroll
        for (int mt = 0; mt < 4; ++mt)
#pragma unroll
            for (int r = 0; r < 4; ++r) {
                const float p = exp2v(fminf(S[mt][r], 43.28085f));
                S[mt][r] = p;
                l += p;
            }

        // ---- P -> wave-private dbuf LDS strip via cvt_pk, read as B-frags ----
        const int pp = st & 1;
#pragma unroll
        for (int mt = 0; mt < 4; ++mt) {
            uint2v w;
            w[0] = cvtpk(S[mt][0], S[mt][1]);
            w[1] = cvtpk(S[mt][2], S[mt][3]);
            *(uint2v*)&Ps[wave][pp][n][mt * 16 + quad * 4] = w;
        }
        asm volatile("s_waitcnt lgkmcnt(0)" ::: "memory");   // wave-private; no barrier
        const short8 bP0 = *(const short8*)&Ps[wave][pp][n][quad * 8];
        const short8 bP1 = *(const short8*)&Ps[wave][pp][n][32 + quad * 8];

        // ---- O^T += V^T P^T (this wave's 2 ht) ----
#pragma unroll
        for (int h = 0; h < 2; ++h) {
            O[h] = __builtin_amdgcn_mfma_f32_16x16x32_bf16(vA[h], bP0, O[h], 0, 0, 0);
            O[h] = __builtin_amdgcn_mfma_f32_16x16x32_bf16(vB[h], bP1, O[h], 0, 0, 0);
        }
    }

    // ---- l: reduce across the 4 quads holding this q-row ----
    l += __shfl_xor(l, 16);
    l += __shfl_xor(l, 32);

    if (nc == 1) {
        const float inv = 1.0f / l;
        float* op = out + ((size_t)b * TT + qrow) * HH;
#pragma unroll
        for (int h = 0; h < 2; ++h) {
            const int ht = dhalf * 2 + h;
            float4 o4;
            o4.x = O[h][0] * inv;
            o4.y = O[h][1] * inv;
            o4.z = O[h][2] * inv;
            o4.w = O[h][3] * inv;
            *(float4*)(op + ht * 16 + quad * 4) = o4;
        }
    } else {
        float* sb = scr + (size_t)(b * 576 + soff_strip(qs) + ci) * 1040;
        float* rp = sb + n * 64;
#pragma unroll
        for (int h = 0; h < 2; ++h) {
            const int ht = dhalf * 2 + h;
            *(f32x4*)(rp + ht * 16 + quad * 4) = O[h];   // unnormalized
        }
        if (dhalf == 0 && quad == 0) sb[1024 + n] = l;
    }
}

// ---------------------------------------------------------------------------
// Kernel 3: combine partials for strips qs >= 64. 768 blocks x 64 thr.
// ---------------------------------------------------------------------------
__global__ __launch_bounds__(64) void combine_kernel(
    const float* __restrict__ scr,
    float* __restrict__ out)
{
    const int b  = blockIdx.x / 192;
    const int qs = 64 + blockIdx.x % 192;
    const int nc = ((qs >> 2) + 16) >> 4;
    const int base = b * 576 + soff_strip(qs);

    const int t    = threadIdx.x;
    const int row  = t >> 2;
    const int col0 = (t & 3) * 16;

    f32x4 s0 = (f32x4){0.f,0.f,0.f,0.f}, s1 = s0, s2 = s0, s3 = s0;
    float lsum = 0.f;
    for (int ci = 0; ci < nc; ++ci) {
        const float* sb = scr + (size_t)(base + ci) * 1040;
        lsum += sb[1024 + row];
        const float* p = sb + row * 64 + col0;
        s0 += *(const f32x4*)(p);
        s1 += *(const f32x4*)(p + 4);
        s2 += *(const f32x4*)(p + 8);
        s3 += *(const f32x4*)(p + 12);
    }
    const float inv = 1.0f / lsum;
    float* op = out + ((size_t)b * TT + qs * 16 + row) * HH + col0;
    *(f32x4*)(op)      = s0 * inv;
    *(f32x4*)(op + 4)  = s1 * inv;
    *(f32x4*)(op + 8)  = s2 * inv;
    *(f32x4*)(op + 12) = s3 * inv;
}

// ---------------------------------------------------------------------------
// ws layout (~16 MB): [Qb 2MB][Wf 384KB][Kf 2MB][Vf 2MB][scr 9.585MB]
// ---------------------------------------------------------------------------
extern "C" void kernel_launch(void* const* d_in, const int* in_sizes, int n_in,
                              void* d_out, int out_size, void* d_ws, size_t ws_size,
                              hipStream_t stream)
{
    const float* x  = (const float*)d_in[0];
    const float* Wq = (const float*)d_in[1];
    const float* Wk = (const float*)d_in[2];
    const float* Wv = (const float*)d_in[3];

    unsigned short* Qb = (unsigned short*)d_ws;                    // 2 MB
    unsigned short* Wf = Qb + (size_t)BB * TT * HH;                // 384 KB
    unsigned short* Kf = Wf + (size_t)192 * 1024;                  // 2 MB
    unsigned short* Vf = Kf + (size_t)BB * 262144;                 // 2 MB
    float*          scr = (float*)(Vf + (size_t)BB * 262144);      // 9.585 MB
    float* out = (float*)d_out;

    wtrans_kernel<<<96, 256, 0, stream>>>(Wq, Wk, Wv, Wf);
    qkv_gemm<<<BB * TT / 64, 512, 0, stream>>>(x, Wf, Qb, Kf, Vf);
    attn_kernel<<<1280, 256, 0, stream>>>(Qb, Kf, Vf, out, scr);
    combine_kernel<<<768, 64, 0, stream>>>(scr, out);
}

// Round 13
// 144.543 us; speedup vs baseline: 1.0724x; 1.0724x over previous
//
#include <hip/hip_runtime.h>
#include <hip/hip_bf16.h>
#include <math.h>

#define BB 4
#define TT 4096
#define CC 1024
#define HH 64

typedef __attribute__((ext_vector_type(8))) short short8;          // MFMA A/B frag (8 bf16)
typedef __attribute__((ext_vector_type(8))) unsigned short ushort8;
typedef __attribute__((ext_vector_type(4))) float f32x4;           // MFMA C/D frag
typedef __attribute__((ext_vector_type(2))) unsigned int uint2v;   // 8B mover
typedef __attribute__((ext_vector_type(4))) unsigned int uint4v;   // 16B pack

// RNE float->bf16 (bit-trick; used in non-hot paths)
__device__ inline unsigned short f2bf(float f) {
    unsigned int u = __builtin_bit_cast(unsigned int, f);
    unsigned int r = u + 0x7fffu + ((u >> 16) & 1u);
    return (unsigned short)(r >> 16);
}

// packed RNE float2->bf16x2 (hot loops; identical rounding to f2bf)
__device__ inline unsigned int cvtpk(float lo, float hi) {
    unsigned int r;
    asm("v_cvt_pk_bf16_f32 %0, %1, %2" : "=v"(r) : "v"(lo), "v"(hi));
    return r;
}

// native 2^x (single VOP1 transcendental)
__device__ inline float exp2v(float x) {
    float r;
    asm("v_exp_f32 %0, %1" : "=v"(r) : "v"(x));
    return r;
}

// async global->LDS, 16B per lane. LDS dest = wave-uniform base + lane*16.
__device__ inline void gll16(const void* g, void* l) {
    __builtin_amdgcn_global_load_lds(
        (const __attribute__((address_space(1))) unsigned int*)g,
        (__attribute__((address_space(3))) unsigned int*)l,
        16, 0, 0);
}

// scratch-slot offset within a batch for 16-row strip qs >= 64
__device__ inline int soff_strip(int qs) {
    if (qs < 128) return (qs - 64) * 2;
    if (qs < 192) return 128 + (qs - 128) * 3;
    return 320 + (qs - 192) * 4;
}

// ---------------------------------------------------------------------------
// Kernel 0: W -> frag-linear bf16 layout Wf (unchanged, proven).
// ---------------------------------------------------------------------------
__global__ __launch_bounds__(256) void wtrans_kernel(
    const float* __restrict__ Wq,
    const float* __restrict__ Wk,
    const float* __restrict__ Wv,
    unsigned short* __restrict__ Wf)
{
    const int t = blockIdx.x * 256 + threadIdx.x;   // 0..24575
    const int lane = t & 63;
    const int ntl  = (t >> 6) % 12;
    const int kt   = t / 768;
    const int quad = lane >> 4, n = lane & 15;
    const int m    = ntl >> 2;
    const int col  = (ntl & 3) * 16 + n;
    const float* src = (m == 0) ? Wq : (m == 1) ? Wk : Wv;
    ushort8 u;
#pragma unroll
    for (int j = 0; j < 8; ++j)
        u[j] = f2bf(src[(kt * 32 + quad * 8 + j) * 64 + col]);
    *(ushort8*)(Wf + (size_t)t * 8) = u;
}

// ---------------------------------------------------------------------------
// Kernel 1: QKV GEMM. R17 depth-2 counted-vmcnt structure + R20 exp2-domain
// Q pre-scale (unchanged from the 145.6us best).
// ---------------------------------------------------------------------------
__global__ __launch_bounds__(512, 2) void qkv_gemm(
    const float* __restrict__ x,
    const unsigned short* __restrict__ Wf,
    unsigned short* __restrict__ Qb,
    unsigned short* __restrict__ Kf,
    unsigned short* __restrict__ Vf)
{
    // buf bb at bb*40960: x[64][64] f32 @ +0 (16KB), Wf 24 frags @ +16384 (24KB)
    __shared__ __align__(16) unsigned char smem[122880];   // 3 bufs x 40KB
    float (*Tl)[200] = (float (*)[200])smem;   // epilogue overlay [64][200] (51.2KB)

    const int tid  = threadIdx.x;
    const int lane = tid & 63;
    const int wave = tid >> 6;          // 0..7
    const int n    = lane & 15;
    const int quad = lane >> 4;
    const int mt   = wave & 3;          // m-tile (16 rows)
    const int ch   = wave >> 2;         // col half (96 cols)

    const int row0g = blockIdx.x * 64;  // global row base (full st strip)
    const int b     = row0g >> 12;
    const int st    = (row0g & (TT - 1)) >> 6;

    const char* xg = (const char*)(x + (size_t)row0g * CC);
    const char* wg = (const char*)Wf;

    f32x4 acc[6];
#pragma unroll
    for (int i = 0; i < 6; ++i) acc[i] = (f32x4){0.f, 0.f, 0.f, 0.f};

    // ---- staging: 5 global_load_lds per thread per K-step ----
    auto stage = [&](int bb, int s) {
        unsigned char* base = smem + bb * 40960;
#pragma unroll
        for (int i = 0; i < 2; ++i) {
            const int rr = (i * 8 + wave) * 4 + (lane >> 4);
            const int cb = ((lane & 15) * 16) ^ ((rr & 7) << 4);
            gll16(xg + (size_t)rr * 4096 + s * 256 + cb,
                  base + (i * 8 + wave) * 1024);
        }
#pragma unroll
        for (int i = 0; i < 3; ++i) {
            const int off = (i * 8 + wave) * 1024;
            gll16(wg + (size_t)s * 24576 + off + lane * 16,
                  base + 16384 + off);
        }
    };

    // ---- compute one K-step from buf bb (LDS only; no VMEM ops) ----
    auto compute = [&](int bb) {
        const unsigned char* xb = smem + bb * 40960;
        const unsigned char* wb = xb + 16384;
        const int row = mt * 16 + n;
        const int swz = (n & 7) << 4;
#pragma unroll
        for (int ktl = 0; ktl < 2; ++ktl) {
            const int c0 = (ktl * 128 + quad * 32) ^ swz;
            const int c1 = (ktl * 128 + quad * 32 + 16) ^ swz;
            const float4 f0 = *(const float4*)(xb + row * 256 + c0);
            const float4 f1 = *(const float4*)(xb + row * 256 + c1);
            uint4v u;
            u[0] = cvtpk(f0.x, f0.y);
            u[1] = cvtpk(f0.z, f0.w);
            u[2] = cvtpk(f1.x, f1.y);
            u[3] = cvtpk(f1.z, f1.w);
            const short8 a0 = __builtin_bit_cast(short8, u);
#pragma unroll
            for (int t = 0; t < 6; ++t) {
                const int g = ch * 6 + t;
                const short8 bwv = *(const short8*)(wb + (ktl * 12 + g) * 1024 + lane * 16);
                acc[t] = __builtin_amdgcn_mfma_f32_16x16x32_bf16(a0, bwv, acc[t], 0, 0, 0);
            }
        }
    };

    // ---- counted-vmcnt pipelined K loop (16 steps of K=64, depth 2) ----
    stage(0, 0);
    stage(1, 1);
#pragma unroll
    for (int s = 0; s < 16; ++s) {
        if (s + 2 < 16) stage((s + 2) % 3, s + 2);
        if (s <= 13)      asm volatile("s_waitcnt vmcnt(10)" ::: "memory");
        else if (s == 14) asm volatile("s_waitcnt vmcnt(5)"  ::: "memory");
        else              asm volatile("s_waitcnt vmcnt(0)"  ::: "memory");
        __builtin_amdgcn_sched_barrier(0);
        __builtin_amdgcn_s_barrier();     // all waves' stage-s data in LDS
        compute(s % 3);
        __builtin_amdgcn_s_barrier();     // all waves done reading buf s%3
    }

    // ---- deposit acc into Tl (overlays staging; all reads are done) ----
#pragma unroll
    for (int t = 0; t < 6; ++t) {
        const int g   = ch * 6 + t;
        const int col = (g >> 2) * 64 + (g & 3) * 16 + n;
#pragma unroll
        for (int r = 0; r < 4; ++r)
            Tl[mt * 16 + quad * 4 + r][col] = acc[t][r];
    }
    __syncthreads();

    // ---- epilogue ----
    // Q: row-major bf16, pre-scaled by C^-0.5 * log2(e) for exp2-domain attn.
    {
        const int row = tid & 63;
        const int c0  = (tid >> 6) * 8;
        const float qsc = 0.045084220f;   // (1/32) * log2(e)
        uint4v w4;
        w4[0] = cvtpk(Tl[row][c0]     * qsc, Tl[row][c0 + 1] * qsc);
        w4[1] = cvtpk(Tl[row][c0 + 2] * qsc, Tl[row][c0 + 3] * qsc);
        w4[2] = cvtpk(Tl[row][c0 + 4] * qsc, Tl[row][c0 + 5] * qsc);
        w4[3] = cvtpk(Tl[row][c0 + 6] * qsc, Tl[row][c0 + 7] * qsc);
        *(uint4v*)(Qb + (size_t)(row0g + row) * HH + c0) = w4;
    }
    // K frag-linear: wave -> frag (mt2 = wave>>1, kk = wave&1)
    {
        const int mt2 = wave >> 1, kk = wave & 1;
        ushort8 u;
#pragma unroll
        for (int j = 0; j < 8; ++j)
            u[j] = f2bf(Tl[mt2 * 16 + n][64 + kk * 32 + quad * 8 + j]);
        const size_t r = (size_t)(((b * 64 + st) * 4 + mt2) * 2 + kk) * 64 + lane;
        *(ushort8*)(Kf + r * 8) = u;
    }
    // V frag-linear (V^T frags): wave -> frag (ht = wave>>1, kv = wave&1)
    {
        const int ht = wave >> 1, kv = wave & 1;
        ushort8 u;
#pragma unroll
        for (int j = 0; j < 8; ++j)
            u[j] = f2bf(Tl[kv * 32 + quad * 8 + j][128 + ht * 16 + n]);
        const size_t r = (size_t)(((b * 64 + st) * 4 + ht) * 2 + kv) * 64 + lane;
        *(ushort8*)(Vf + r * 8) = u;
    }
}

// ---------------------------------------------------------------------------
// Kernel 2: flash attention. R22: PV pipelined one iteration behind.
// R21's d-split REVERTED (work-bound: doubling waves with 1.8x work cost
// 1.6x). The remaining serial segment per iter was the in-iteration LDS P
// round-trip (write -> lgkmcnt(0) drain -> read -> PV, ~150-250cy x 33k
// iters). Now iter st does: read P(st-1) from Ps[(st-1)&1] (written a full
// iteration ago -> write long complete; read latency hidden under QK^T) ->
// QK^T(st) -> PV(st-1) with V(st-1) held in regs -> load V(st) -> prefetch
// K(st+1) -> mask/softmax -> write Ps[st&1]. Explicit lgkmcnt(0) deleted
// (wave-private in-order LDS queue + compiler minimal waits). Prologue does
// st0's QK/softmax/write; epilogue does the final PV. Single-iter chunks
// (st0==stEnd) = prologue+epilogue only.
// Keeps R20: exp2 softmax, cvtpk packing, padded Ps, launch reversal.
// ---------------------------------------------------------------------------
__global__ __launch_bounds__(256) void attn_kernel(
    const unsigned short* __restrict__ Qb,
    const unsigned short* __restrict__ Kf,
    const unsigned short* __restrict__ Vf,
    float* __restrict__ out,
    float* __restrict__ scr)
{
    __shared__ unsigned short Ps[4][2][16][76];   // per-wave dbuf P strip (padded)

    const int tid  = threadIdx.x;
    const int lane = tid & 63;
    const int wave = tid >> 6;
    const int n    = lane & 15;
    const int quad = lane >> 4;

    const int wid = blockIdx.x * 4 + wave;     // 0..2559
    const int b   = wid / 640;
    const int u   = 639 - (wid - b * 640);     // reversed: long chunks first

    // prefix-sum inverse: u -> (qs, ci), nc(qs) = (qs>>2 + 16)>>4
    int qs, ci;
    if (u < 64)        { qs = u;                  ci = 0; }
    else if (u < 192)  { const int v = u - 64;  qs = 64  + (v >> 1); ci = v & 1; }
    else if (u < 384)  { const int v = u - 192; const int d = v / 3;
                         qs = 128 + d;            ci = v - 3 * d; }
    else               { const int v = u - 384; qs = 192 + (v >> 2); ci = v & 3; }

    const int stmax = qs >> 2;
    const int st0   = ci << 4;
    const int stEnd = min(stmax, st0 + 15);
    const int nc    = (stmax + 16) >> 4;
    const int qrow  = qs * 16 + n;

    // Q^T B-frags resident (Q pre-scaled by C^-0.5 * log2e)
    const unsigned short* qp = Qb + ((size_t)b * TT + qrow) * HH;
    const short8 bQ0 = *(const short8*)(qp + quad * 8);
    const short8 bQ1 = *(const short8*)(qp + 32 + quad * 8);

    const unsigned short* KfB = Kf + (size_t)b * 262144;
    const unsigned short* VfB = Vf + (size_t)b * 262144;

    f32x4 O[4];
#pragma unroll
    for (int ht = 0; ht < 4; ++ht) O[ht] = (f32x4){0.f, 0.f, 0.f, 0.f};
    float l = 0.f;

    // preload K frags for st0
    short8 kA[4], kB[4];
#pragma unroll
    for (int mt = 0; mt < 4; ++mt) {
        const unsigned short* kp = KfB + (size_t)((st0 * 4 + mt) * 2) * 512 + lane * 8;
        kA[mt] = *(const short8*)(kp);
        kB[mt] = *(const short8*)(kp + 512);
    }
    short8 vA[4], vB[4];

    // helper macros inlined as lambdas
    auto qk_mask_softmax_write = [&](int st, f32x4* S) {
        // S^T = K Q^T from resident K frags (log2-domain)
#pragma unroll
        for (int mt = 0; mt < 4; ++mt) {
            f32x4 acc = (f32x4){0.f, 0.f, 0.f, 0.f};
            acc = __builtin_amdgcn_mfma_f32_16x16x32_bf16(kA[mt], bQ0, acc, 0, 0, 0);
            acc = __builtin_amdgcn_mfma_f32_16x16x32_bf16(kB[mt], bQ1, acc, 0, 0, 0);
            S[mt] = acc;
        }
    };

    // ---------------- prologue: iteration st0 (no PV yet) ----------------
    {
        const int st = st0;
        f32x4 S[4];
        qk_mask_softmax_write(st, S);

        // load V(st0) (consumed by PV one iteration later)
#pragma unroll
        for (int ht = 0; ht < 4; ++ht) {
            const unsigned short* vp = VfB + (size_t)((st * 4 + ht) * 2) * 512 + lane * 8;
            vA[ht] = *(const short8*)(vp);
            vB[ht] = *(const short8*)(vp + 512);
        }
        // K prefetch for st0+1
        if (st < stEnd) {
#pragma unroll
            for (int mt = 0; mt < 4; ++mt) {
                const unsigned short* kp = KfB + (size_t)(((st + 1) * 4 + mt) * 2) * 512 + lane * 8;
                kA[mt] = *(const short8*)(kp);
                kB[mt] = *(const short8*)(kp + 512);
            }
        }
        // causal mask (st0 can be the diag tile)
        if (st == stmax) {
#pragma unroll
            for (int mt = 0; mt < 4; ++mt) {
                const int sg = st * 64 + mt * 16 + quad * 4;
#pragma unroll
                for (int r = 0; r < 4; ++r)
                    if (sg + r > qrow) S[mt][r] = -INFINITY;
            }
        }
        // softmax accumulate
#pragma unroll
        for (int mt = 0; mt < 4; ++mt)
#pragma unroll
            for (int r = 0; r < 4; ++r) {
                const float p = exp2v(fminf(S[mt][r], 43.28085f));
                S[mt][r] = p;
                l += p;
            }
        // write P(st0) -> Ps[st0&1]
        const int pp = st & 1;
#pragma unroll
        for (int mt = 0; mt < 4; ++mt) {
            uint2v w;
            w[0] = cvtpk(S[mt][0], S[mt][1]);
            w[1] = cvtpk(S[mt][2], S[mt][3]);
            *(uint2v*)&Ps[wave][pp][n][mt * 16 + quad * 4] = w;
        }
    }

    // ---------------- main loop: PV runs one iteration behind ----------------
    for (int st = st0 + 1; st <= stEnd; ++st) {
        // read P(st-1) — written a full iteration ago; latency hides under QK
        const unsigned short* prow = &Ps[wave][(st - 1) & 1][n][0];
        const short8 bP0 = *(const short8*)(prow + quad * 8);
        const short8 bP1 = *(const short8*)(prow + 32 + quad * 8);

        // QK^T(st) from prefetched K frags (independent of the P read)
        f32x4 S[4];
        qk_mask_softmax_write(st, S);

        // PV(st-1): O += V(st-1)^T P(st-1)^T  (vA/vB hold V(st-1))
#pragma unroll
        for (int ht = 0; ht < 4; ++ht) {
            O[ht] = __builtin_amdgcn_mfma_f32_16x16x32_bf16(vA[ht], bP0, O[ht], 0, 0, 0);
            O[ht] = __builtin_amdgcn_mfma_f32_16x16x32_bf16(vB[ht], bP1, O[ht], 0, 0, 0);
        }

        // load V(st) for next iteration's PV
#pragma unroll
        for (int ht = 0; ht < 4; ++ht) {
            const unsigned short* vp = VfB + (size_t)((st * 4 + ht) * 2) * 512 + lane * 8;
            vA[ht] = *(const short8*)(vp);
            vB[ht] = *(const short8*)(vp + 512);
        }
        // K prefetch for st+1
        if (st < stEnd) {
#pragma unroll
            for (int mt = 0; mt < 4; ++mt) {
                const unsigned short* kp = KfB + (size_t)(((st + 1) * 4 + mt) * 2) * 512 + lane * 8;
                kA[mt] = *(const short8*)(kp);
                kB[mt] = *(const short8*)(kp + 512);
            }
        }

        // causal mask (diag tile)
        if (st == stmax) {
#pragma unroll
            for (int mt = 0; mt < 4; ++mt) {
                const int sg = st * 64 + mt * 16 + quad * 4;
#pragma unroll
                for (int r = 0; r < 4; ++r)
                    if (sg + r > qrow) S[mt][r] = -INFINITY;
            }
        }
        // softmax accumulate
#pragma unroll
        for (int mt = 0; mt < 4; ++mt)
#pragma unroll
            for (int r = 0; r < 4; ++r) {
                const float p = exp2v(fminf(S[mt][r], 43.28085f));
                S[mt][r] = p;
                l += p;
            }
        // write P(st) -> Ps[st&1]
        const int pp = st & 1;
#pragma unroll
        for (int mt = 0; mt < 4; ++mt) {
            uint2v w;
            w[0] = cvtpk(S[mt][0], S[mt][1]);
            w[1] = cvtpk(S[mt][2], S[mt][3]);
            *(uint2v*)&Ps[wave][pp][n][mt * 16 + quad * 4] = w;
        }
    }

    // ---------------- epilogue: final PV (stEnd) ----------------
    {
        const unsigned short* prow = &Ps[wave][stEnd & 1][n][0];
        const short8 bP0 = *(const short8*)(prow + quad * 8);
        const short8 bP1 = *(const short8*)(prow + 32 + quad * 8);
#pragma unroll
        for (int ht = 0; ht < 4; ++ht) {
            O[ht] = __builtin_amdgcn_mfma_f32_16x16x32_bf16(vA[ht], bP0, O[ht], 0, 0, 0);
            O[ht] = __builtin_amdgcn_mfma_f32_16x16x32_bf16(vB[ht], bP1, O[ht], 0, 0, 0);
        }
    }

    // ---- l: reduce across the 4 quads holding this q-row ----
    l += __shfl_xor(l, 16);
    l += __shfl_xor(l, 32);

    if (nc == 1) {
        const float inv = 1.0f / l;
        float* op = out + ((size_t)b * TT + qrow) * HH;
#pragma unroll
        for (int ht = 0; ht < 4; ++ht) {
            float4 o4;
            o4.x = O[ht][0] * inv;
            o4.y = O[ht][1] * inv;
            o4.z = O[ht][2] * inv;
            o4.w = O[ht][3] * inv;
            *(float4*)(op + ht * 16 + quad * 4) = o4;
        }
    } else {
        float* sb = scr + (size_t)(b * 576 + soff_strip(qs) + ci) * 1040;
        float* rp = sb + n * 64;
#pragma unroll
        for (int ht = 0; ht < 4; ++ht)
            *(f32x4*)(rp + ht * 16 + quad * 4) = O[ht];   // unnormalized
        if (quad == 0) sb[1024 + n] = l;
    }
}

// ---------------------------------------------------------------------------
// Kernel 3: combine partials for strips qs >= 64. 768 blocks x 64 thr.
// ---------------------------------------------------------------------------
__global__ __launch_bounds__(64) void combine_kernel(
    const float* __restrict__ scr,
    float* __restrict__ out)
{
    const int b  = blockIdx.x / 192;
    const int qs = 64 + blockIdx.x % 192;
    const int nc = ((qs >> 2) + 16) >> 4;
    const int base = b * 576 + soff_strip(qs);

    const int t    = threadIdx.x;
    const int row  = t >> 2;
    const int col0 = (t & 3) * 16;

    f32x4 s0 = (f32x4){0.f,0.f,0.f,0.f}, s1 = s0, s2 = s0, s3 = s0;
    float lsum = 0.f;
    for (int ci = 0; ci < nc; ++ci) {
        const float* sb = scr + (size_t)(base + ci) * 1040;
        lsum += sb[1024 + row];
        const float* p = sb + row * 64 + col0;
        s0 += *(const f32x4*)(p);
        s1 += *(const f32x4*)(p + 4);
        s2 += *(const f32x4*)(p + 8);
        s3 += *(const f32x4*)(p + 12);
    }
    const float inv = 1.0f / lsum;
    float* op = out + ((size_t)b * TT + qs * 16 + row) * HH + col0;
    *(f32x4*)(op)      = s0 * inv;
    *(f32x4*)(op + 4)  = s1 * inv;
    *(f32x4*)(op + 8)  = s2 * inv;
    *(f32x4*)(op + 12) = s3 * inv;
}

// ---------------------------------------------------------------------------
// ws layout (~16 MB): [Qb 2MB][Wf 384KB][Kf 2MB][Vf 2MB][scr 9.585MB]
// ---------------------------------------------------------------------------
extern "C" void kernel_launch(void* const* d_in, const int* in_sizes, int n_in,
                              void* d_out, int out_size, void* d_ws, size_t ws_size,
                              hipStream_t stream)
{
    const float* x  = (const float*)d_in[0];
    const float* Wq = (const float*)d_in[1];
    const float* Wk = (const float*)d_in[2];
    const float* Wv = (const float*)d_in[3];

    unsigned short* Qb = (unsigned short*)d_ws;                    // 2 MB
    unsigned short* Wf = Qb + (size_t)BB * TT * HH;                // 384 KB
    unsigned short* Kf = Wf + (size_t)192 * 1024;                  // 2 MB
    unsigned short* Vf = Kf + (size_t)BB * 262144;                 // 2 MB
    float*          scr = (float*)(Vf + (size_t)BB * 262144);      // 9.585 MB
    float* out = (float*)d_out;

    wtrans_kernel<<<96, 256, 0, stream>>>(Wq, Wk, Wv, Wf);
    qkv_gemm<<<BB * TT / 64, 512, 0, stream>>>(x, Wf, Qb, Kf, Vf);
    attn_kernel<<<640, 256, 0, stream>>>(Qb, Kf, Vf, out, scr);
    combine_kernel<<<768, 64, 0, stream>>>(scr, out);
}